// Round 2
// baseline (2493.096 us; speedup 1.0000x reference)
//
#include <hip/hip_runtime.h>
#include <math.h>

#define NB   1024
#define NH   8
#define NDK  64
#define NDM  512
#define NP   49

#define BM 128
#define BN 128
#define BK 16

// C[M][N] = A[M][K] @ B[N][K]^T + bias[N]   (both A and B are K-major)
__global__ __launch_bounds__(256) void sgemm_nt(
    const float* __restrict__ A,
    const float* __restrict__ B,
    const float* __restrict__ bias,
    float* __restrict__ C,
    int M, int N, int K)
{
    __shared__ float As[BK][BM + 4];
    __shared__ float Bs[BK][BN + 4];
    const int t  = threadIdx.x;
    const int tx = t & 15, ty = t >> 4;
    const int bm = blockIdx.y * BM, bn = blockIdx.x * BN;
    const float* Ab = A + (size_t)bm * K;
    const float* Bb = B + (size_t)bn * K;

    float acc[8][8];
#pragma unroll
    for (int i = 0; i < 8; ++i)
#pragma unroll
        for (int j = 0; j < 8; ++j) acc[i][j] = 0.f;

    for (int kt = 0; kt < K; kt += BK) {
#pragma unroll
        for (int u = 0; u < 2; ++u) {
            const int f   = t + u * 256;
            const int row = f >> 2;
            const int c0  = (f & 3) << 2;
            const float4 av = *(const float4*)(Ab + (size_t)row * K + kt + c0);
            const float4 bv = *(const float4*)(Bb + (size_t)row * K + kt + c0);
            As[c0 + 0][row] = av.x; As[c0 + 1][row] = av.y;
            As[c0 + 2][row] = av.z; As[c0 + 3][row] = av.w;
            Bs[c0 + 0][row] = bv.x; Bs[c0 + 1][row] = bv.y;
            Bs[c0 + 2][row] = bv.z; Bs[c0 + 3][row] = bv.w;
        }
        __syncthreads();
#pragma unroll
        for (int kk = 0; kk < BK; ++kk) {
            float a[8], b[8];
#pragma unroll
            for (int i = 0; i < 8; ++i) a[i] = As[kk][ty * 8 + i];
#pragma unroll
            for (int j = 0; j < 8; ++j) b[j] = Bs[kk][tx * 8 + j];
#pragma unroll
            for (int i = 0; i < 8; ++i)
#pragma unroll
                for (int j = 0; j < 8; ++j) acc[i][j] += a[i] * b[j];
        }
        __syncthreads();
    }

#pragma unroll
    for (int i = 0; i < 8; ++i) {
        const int r = bm + ty * 8 + i;
        float* Crow = C + (size_t)r * N + bn + tx * 8;
#pragma unroll
        for (int j4 = 0; j4 < 2; ++j4) {
            const int cb = bn + tx * 8 + j4 * 4;
            float4 o;
            o.x = acc[i][j4 * 4 + 0] + bias[cb + 0];
            o.y = acc[i][j4 * 4 + 1] + bias[cb + 1];
            o.z = acc[i][j4 * 4 + 2] + bias[cb + 2];
            o.w = acc[i][j4 * 4 + 3] + bias[cb + 3];
            *(float4*)(Crow + j4 * 4) = o;
        }
    }
}

__device__ __forceinline__ float wsum(float x) {
#pragma unroll
    for (int m = 32; m; m >>= 1) x += __shfl_xor(x, m);
    return x;
}
__device__ __forceinline__ float wmax(float x) {
#pragma unroll
    for (int m = 32; m; m >>= 1) x = fmaxf(x, __shfl_xor(x, m));
    return x;
}

// One block per (b,h). q/k/v buffers are [b][49][h*64+d] (GEMM layout).
// mid may alias qbuf: each block writes only the h-slice it alone reads.
// LDS: qs (q, later overlaid with v), ks, ss (scores -> p in place).
__global__ __launch_bounds__(256, 4) void attn_mid(
    const float* __restrict__ qb,
    const float* __restrict__ kb,
    const float* __restrict__ vb,
    const float* __restrict__ Wg,
    const float* __restrict__ Vg,
    float* __restrict__ mid)
{
    const int bh = blockIdx.x;
    const int b = bh >> 3, h = bh & 7;

    __shared__ float qs[52][68];   // phase 1: q ; phase 3: v (overlay)
    __shared__ float ks[52][68];
    __shared__ float ss[52][52];   // scores, then p in place
    __shared__ float vRl[16];

    const int t    = threadIdx.x;
    const int lane = t & 63;
    const int wv   = t >> 6;

    if (t < 13) {  // gate table: (1+e^V)/(1+e^(V - W*R)), R in [0,12]
        const float Wh = Wg[h], Vh = Vg[h];
        vRl[t] = (1.f + expf(Vh)) / (1.f + expf(Vh - Wh * (float)t));
    }

    const size_t base = ((size_t)b * NP) * NDM + (size_t)h * NDK;

    // ---- load q,k -> LDS; prefetch v -> registers (written to qs later) ----
    float4 vr[4];
#pragma unroll
    for (int u = 0; u < 4; ++u) {
        const int i = t + (u << 8);
        if (i < NP * 16) {
            const int pos = i >> 4;
            const int c0  = (i & 15) << 2;
            const size_t off = base + (size_t)pos * NDM + c0;
            *(float4*)&qs[pos][c0] = *(const float4*)(qb + off);
            *(float4*)&ks[pos][c0] = *(const float4*)(kb + off);
            vr[u] = *(const float4*)(vb + off);
        }
    }
    __syncthreads();

    // ---- phase 1: ss = 0.125 * q @ k^T (exact: 0.125 is a power of 2) ----
    if (t < 169) {
        const int r0 = (t / 13) * 4;
        const int c0 = (t % 13) * 4;
        float acc[4][4];
#pragma unroll
        for (int i = 0; i < 4; ++i)
#pragma unroll
            for (int j = 0; j < 4; ++j) acc[i][j] = 0.f;
        for (int kk = 0; kk < NDK; kk += 4) {
            float4 a[4], bb[4];
#pragma unroll
            for (int i = 0; i < 4; ++i) a[i]  = *(const float4*)&qs[r0 + i][kk];
#pragma unroll
            for (int j = 0; j < 4; ++j) bb[j] = *(const float4*)&ks[c0 + j][kk];
#pragma unroll
            for (int i = 0; i < 4; ++i)
#pragma unroll
                for (int j = 0; j < 4; ++j)
                    acc[i][j] += a[i].x * bb[j].x + a[i].y * bb[j].y
                               + a[i].z * bb[j].z + a[i].w * bb[j].w;
        }
#pragma unroll
        for (int i = 0; i < 4; ++i) {
            float4 o;
            o.x = acc[i][0] * 0.125f; o.y = acc[i][1] * 0.125f;
            o.z = acc[i][2] * 0.125f; o.w = acc[i][3] * 0.125f;
            *(float4*)&ss[r0 + i][c0] = o;
        }
    }
    __syncthreads();

    // ---- overlay: v regs -> qs (q is dead now) ----
#pragma unroll
    for (int u = 0; u < 4; ++u) {
        const int i = t + (u << 8);
        if (i < NP * 16) {
            const int pos = i >> 4;
            const int c0  = (i & 15) << 2;
            *(float4*)&qs[pos][c0] = vr[u];
        }
    }

    // ---- phase 2: wave-parallel per-row top-k/softmax/map/gate/softmax2 ----
    // lane = column; rows round-robin over the 4 waves.
    const int ci = lane / 7, cj = lane % 7;     // meaningful for lane < 49
    for (int r = wv; r < NP; r += 4) {
        const float x0 = (lane < NP) ? ss[r][lane] : -INFINITY;

        // bitonic sort ascending across 64 lanes (15 pad -INF sort low)
        float x = x0;
#pragma unroll
        for (int k = 2; k <= 64; k <<= 1) {
#pragma unroll
            for (int j = k >> 1; j > 0; j >>= 1) {
                const float y = __shfl_xor(x, j);
                const bool takeMin = ((lane & k) == 0) == ((lane & j) == 0);
                x = takeMin ? fminf(x, y) : fmaxf(x, y);
            }
        }
        const float kth = __shfl(x, 53);   // 11th largest = 39th smallest
        const float m1  = __shfl(x, 63);   // row max

        // softmax #1 over kept entries + expectation of (fi,fj)
        const bool  keep = (lane < NP) && (x0 >= kth);
        const float e   = keep ? expf(x0 - m1) : 0.f;
        const float s   = wsum(e);
        const float smi = wsum(e * (float)ci);
        const float smj = wsum(e * (float)cj);
        const int pi = (int)rintf(smi / s);     // round-half-even == jnp.round
        const int pj = (int)rintf(smj / s);

        // gate: l = relu(scores)*vR*scale == relu(ss)*vR (bit-exact equiv)
        const int   R = abs(pi - ci) + abs(pj - cj);
        const float l = (lane < NP) ? fmaxf(x0, 0.f) * vRl[R] : -INFINITY;

        // softmax #2, normalized in place
        const float m2 = wmax(l);
        const float e2 = (lane < NP) ? expf(l - m2) : 0.f;
        const float s2 = wsum(e2);
        if (lane < NP) ss[r][lane] = e2 / s2;
    }
    __syncthreads();

    // ---- phase 3: mid_slice = p @ v ----
    if (t < 208) {
        const int tr = t >> 4;           // row group: rows 4tr..4tr+3
        const int d0 = (t & 15) << 2;    // output dims d0..d0+3
        float acc[4][4];
#pragma unroll
        for (int i = 0; i < 4; ++i)
#pragma unroll
            for (int j = 0; j < 4; ++j) acc[i][j] = 0.f;
        for (int c = 0; c < NP; ++c) {
            const float4 vv = *(const float4*)&qs[c][d0];
            float p[4];
#pragma unroll
            for (int i = 0; i < 4; ++i) p[i] = ss[4 * tr + i][c];
#pragma unroll
            for (int i = 0; i < 4; ++i) {
                acc[i][0] += p[i] * vv.x;
                acc[i][1] += p[i] * vv.y;
                acc[i][2] += p[i] * vv.z;
                acc[i][3] += p[i] * vv.w;
            }
        }
#pragma unroll
        for (int i = 0; i < 4; ++i) {
            const int r = 4 * tr + i;
            if (r < NP) {
                float4 o;
                o.x = acc[i][0]; o.y = acc[i][1];
                o.z = acc[i][2]; o.w = acc[i][3];
                *(float4*)(mid + base + (size_t)r * NDM + d0) = o;
            }
        }
    }
}

extern "C" void kernel_launch(void* const* d_in, const int* in_sizes, int n_in,
                              void* d_out, int out_size, void* d_ws, size_t ws_size,
                              hipStream_t stream)
{
    (void)in_sizes; (void)n_in; (void)out_size; (void)ws_size;
    const float* queries = (const float*)d_in[0];
    const float* keys    = (const float*)d_in[1];
    const float* values  = (const float*)d_in[2];
    const float* Wq = (const float*)d_in[3];
    const float* bq = (const float*)d_in[4];
    const float* Wk = (const float*)d_in[5];
    const float* bk = (const float*)d_in[6];
    const float* Wv = (const float*)d_in[7];
    const float* bv = (const float*)d_in[8];
    const float* Wo = (const float*)d_in[9];
    const float* bo = (const float*)d_in[10];
    const float* Wg = (const float*)d_in[11];
    const float* Vg = (const float*)d_in[12];
    float* out = (float*)d_out;

    float* ws = (float*)d_ws;
    const size_t SZ = (size_t)NB * NP * NDM;   // 25,690,112 elements
    float* qbuf = ws;
    float* kbuf = ws + SZ;
    float* vbuf = ws + 2 * SZ;
    float* mid  = qbuf;                        // safe alias (see attn_mid)

    const int M = NB * NP;                     // 50176
    dim3 blk(256);
    dim3 ggrid(NDM / BN, M / BM);              // (4, 392)

    hipLaunchKernelGGL(sgemm_nt, ggrid, blk, 0, stream, queries, Wq, bq, qbuf, M, NDM, NDM);
    hipLaunchKernelGGL(sgemm_nt, ggrid, blk, 0, stream, keys,    Wk, bk, kbuf, M, NDM, NDM);
    hipLaunchKernelGGL(sgemm_nt, ggrid, blk, 0, stream, values,  Wv, bv, vbuf, M, NDM, NDM);
    hipLaunchKernelGGL(attn_mid, dim3(NB * NH), blk, 0, stream, qbuf, kbuf, vbuf, Wg, Vg, mid);
    hipLaunchKernelGGL(sgemm_nt, ggrid, blk, 0, stream, mid, Wo, bo, out, M, NDM, NDM);
}

// Round 4
// 2038.545 us; speedup vs baseline: 1.2230x; 1.2230x over previous
//
#include <hip/hip_runtime.h>
#include <math.h>

#define NB   1024
#define NH   8
#define NDK  64
#define NDM  512
#define NP   49

// ---------------- fp32 SGEMM (Q/K projections: precision-pinned) ----------
#define BM 128
#define BN 128
#define BK 16

// C[M][N] = A[M][K] @ B[N][K]^T + bias[N]
__global__ __launch_bounds__(256) void sgemm_nt(
    const float* __restrict__ A,
    const float* __restrict__ B,
    const float* __restrict__ bias,
    float* __restrict__ C,
    int M, int N, int K)
{
    __shared__ float As[BK][BM + 4];
    __shared__ float Bs[BK][BN + 4];
    const int t  = threadIdx.x;
    const int tx = t & 15, ty = t >> 4;
    const int bm = blockIdx.y * BM, bn = blockIdx.x * BN;
    const float* Ab = A + (size_t)bm * K;
    const float* Bb = B + (size_t)bn * K;

    float acc[8][8];
#pragma unroll
    for (int i = 0; i < 8; ++i)
#pragma unroll
        for (int j = 0; j < 8; ++j) acc[i][j] = 0.f;

    for (int kt = 0; kt < K; kt += BK) {
#pragma unroll
        for (int u = 0; u < 2; ++u) {
            const int f   = t + u * 256;
            const int row = f >> 2;
            const int c0  = (f & 3) << 2;
            const float4 av = *(const float4*)(Ab + (size_t)row * K + kt + c0);
            const float4 bv = *(const float4*)(Bb + (size_t)row * K + kt + c0);
            As[c0 + 0][row] = av.x; As[c0 + 1][row] = av.y;
            As[c0 + 2][row] = av.z; As[c0 + 3][row] = av.w;
            Bs[c0 + 0][row] = bv.x; Bs[c0 + 1][row] = bv.y;
            Bs[c0 + 2][row] = bv.z; Bs[c0 + 3][row] = bv.w;
        }
        __syncthreads();
#pragma unroll
        for (int kk = 0; kk < BK; ++kk) {
            float a[8], b[8];
#pragma unroll
            for (int i = 0; i < 8; ++i) a[i] = As[kk][ty * 8 + i];
#pragma unroll
            for (int j = 0; j < 8; ++j) b[j] = Bs[kk][tx * 8 + j];
#pragma unroll
            for (int i = 0; i < 8; ++i)
#pragma unroll
                for (int j = 0; j < 8; ++j) acc[i][j] += a[i] * b[j];
        }
        __syncthreads();
    }

#pragma unroll
    for (int i = 0; i < 8; ++i) {
        const int r = bm + ty * 8 + i;
        float* Crow = C + (size_t)r * N + bn + tx * 8;
#pragma unroll
        for (int j4 = 0; j4 < 2; ++j4) {
            const int cb = bn + tx * 8 + j4 * 4;
            float4 o;
            o.x = acc[i][j4 * 4 + 0] + bias[cb + 0];
            o.y = acc[i][j4 * 4 + 1] + bias[cb + 1];
            o.z = acc[i][j4 * 4 + 2] + bias[cb + 2];
            o.w = acc[i][j4 * 4 + 3] + bias[cb + 3];
            *(float4*)(Crow + j4 * 4) = o;
        }
    }
}

// ---------------- bf16 MFMA GEMM (V / O projections: continuous path) -----
#define GBM 128
#define GBN 128
#define GBK 32
#define LDAB 40   // ushort stride = 80 B: 16B-aligned rows, 2-way-conflict-free

typedef __attribute__((ext_vector_type(8))) short bf16x8;
typedef __attribute__((ext_vector_type(4))) float f32x4;

__device__ __forceinline__ unsigned short f2bf(float f) {  // RNE fp32->bf16
    unsigned u = __float_as_uint(f);
    return (unsigned short)((u + 0x7FFF + ((u >> 16) & 1)) >> 16);
}
__device__ __forceinline__ ushort4 f4tobf(float4 v) {
    ushort4 r;
    r.x = f2bf(v.x); r.y = f2bf(v.y); r.z = f2bf(v.z); r.w = f2bf(v.w);
    return r;
}

// C[M][N] = bf16(A[M][K]) @ bf16(B[N][K])^T + bias[N], fp32 accum/output
__global__ __launch_bounds__(256) void mgemm_nt(
    const float* __restrict__ A,
    const float* __restrict__ B,
    const float* __restrict__ bias,
    float* __restrict__ C,
    int M, int N, int K)
{
    __shared__ unsigned short As[GBM][LDAB];
    __shared__ unsigned short Bs[GBN][LDAB];

    const int t    = threadIdx.x;
    const int lane = t & 63;
    const int w    = t >> 6;                 // 4 waves, 2x2
    const int wm   = (w >> 1) * 64;
    const int wn   = (w & 1) * 64;
    const int bm   = blockIdx.y * GBM, bn = blockIdx.x * GBN;

    const int tr = t >> 1;                   // staging: row per thread-pair
    const int th = (t & 1) * 16;             // 16 cols each

    const int fr = lane & 15;                // frag row/col within 16
    const int fq = lane >> 4;                // k-slot 0..3 (8 bf16 each)

    f32x4 acc[4][4];
#pragma unroll
    for (int i = 0; i < 4; ++i)
#pragma unroll
        for (int j = 0; j < 4; ++j) acc[i][j] = (f32x4){0.f, 0.f, 0.f, 0.f};

    const float* Arow = A + (size_t)(bm + tr) * K + th;
    const float* Brow = B + (size_t)(bn + tr) * K + th;

    for (int kt = 0; kt < K; kt += GBK) {
        const float4* pa = (const float4*)(Arow + kt);
        const float4* pb = (const float4*)(Brow + kt);
        float4 a0 = pa[0], a1 = pa[1], a2 = pa[2], a3 = pa[3];
        float4 b0 = pb[0], b1 = pb[1], b2 = pb[2], b3 = pb[3];
        *(ushort4*)&As[tr][th +  0] = f4tobf(a0);
        *(ushort4*)&As[tr][th +  4] = f4tobf(a1);
        *(ushort4*)&As[tr][th +  8] = f4tobf(a2);
        *(ushort4*)&As[tr][th + 12] = f4tobf(a3);
        *(ushort4*)&Bs[tr][th +  0] = f4tobf(b0);
        *(ushort4*)&Bs[tr][th +  4] = f4tobf(b1);
        *(ushort4*)&Bs[tr][th +  8] = f4tobf(b2);
        *(ushort4*)&Bs[tr][th + 12] = f4tobf(b3);
        __syncthreads();

        bf16x8 af[4], bf[4];
#pragma unroll
        for (int fm = 0; fm < 4; ++fm)
            af[fm] = *(const bf16x8*)&As[wm + fm * 16 + fr][fq * 8];
#pragma unroll
        for (int fn = 0; fn < 4; ++fn)
            bf[fn] = *(const bf16x8*)&Bs[wn + fn * 16 + fr][fq * 8];
#pragma unroll
        for (int fm = 0; fm < 4; ++fm)
#pragma unroll
            for (int fn = 0; fn < 4; ++fn)
                acc[fm][fn] = __builtin_amdgcn_mfma_f32_16x16x32_bf16(
                    af[fm], bf[fn], acc[fm][fn], 0, 0, 0);
        __syncthreads();
    }

    // epilogue: D[row][col]: col = lane&15, row = (lane>>4)*4 + reg  (m89)
#pragma unroll
    for (int fn = 0; fn < 4; ++fn) {
        const int col = bn + wn + fn * 16 + fr;
        const float bs = bias[col];
#pragma unroll
        for (int fm = 0; fm < 4; ++fm) {
            const int r0 = bm + wm + fm * 16 + fq * 4;
#pragma unroll
            for (int r = 0; r < 4; ++r)
                C[(size_t)(r0 + r) * N + col] = acc[fm][fn][r] + bs;
        }
    }
}

// ---------------- attention middle ----------------------------------------
__device__ __forceinline__ float wsum(float x) {
#pragma unroll
    for (int m = 32; m; m >>= 1) x += __shfl_xor(x, m);
    return x;
}
__device__ __forceinline__ float wmax(float x) {
#pragma unroll
    for (int m = 32; m; m >>= 1) x = fmaxf(x, __shfl_xor(x, m));
    return x;
}

// One block per (b,h). q/k/v buffers are [b][49][h*64+d] (GEMM layout).
// mid may alias qbuf: each block writes only the h-slice it alone reads.
__global__ __launch_bounds__(256) void attn_mid(
    const float* __restrict__ qb,
    const float* __restrict__ kb,
    const float* __restrict__ vb,
    const float* __restrict__ Wg,
    const float* __restrict__ Vg,
    float* __restrict__ mid)
{
    const int bh = blockIdx.x;
    const int b = bh >> 3, h = bh & 7;

    __shared__ float qs[52][68];
    __shared__ float ks[52][68];
    __shared__ float vs[52][68];
    __shared__ float ss[52][52];   // scores, then p in place
    __shared__ float vRl[16];

    const int t    = threadIdx.x;
    const int lane = t & 63;
    const int wv   = t >> 6;

    if (t < 13) {  // gate table: (1+e^V)/(1+e^(V - W*R)), R in [0,12]
        const float Wh = Wg[h], Vh = Vg[h];
        vRl[t] = (1.f + expf(Vh)) / (1.f + expf(Vh - Wh * (float)t));
    }

    const size_t base = ((size_t)b * NP) * NDM + (size_t)h * NDK;

#pragma unroll
    for (int u = 0; u < 4; ++u) {
        const int i = t + (u << 8);
        if (i < NP * 16) {
            const int pos = i >> 4;
            const int c0  = (i & 15) << 2;
            const size_t off = base + (size_t)pos * NDM + c0;
            *(float4*)&qs[pos][c0] = *(const float4*)(qb + off);
            *(float4*)&ks[pos][c0] = *(const float4*)(kb + off);
            *(float4*)&vs[pos][c0] = *(const float4*)(vb + off);
        }
    }
    __syncthreads();

    // ---- phase 1: ss = 0.125 * q @ k^T (exact: 0.125 is a power of 2) ----
    if (t < 169) {
        const int r0 = (t / 13) * 4;
        const int c0 = (t % 13) * 4;
        float acc[4][4];
#pragma unroll
        for (int i = 0; i < 4; ++i)
#pragma unroll
            for (int j = 0; j < 4; ++j) acc[i][j] = 0.f;
        for (int kk = 0; kk < NDK; kk += 4) {
            float4 a[4], bb[4];
#pragma unroll
            for (int i = 0; i < 4; ++i) a[i]  = *(const float4*)&qs[r0 + i][kk];
#pragma unroll
            for (int j = 0; j < 4; ++j) bb[j] = *(const float4*)&ks[c0 + j][kk];
#pragma unroll
            for (int i = 0; i < 4; ++i)
#pragma unroll
                for (int j = 0; j < 4; ++j)
                    acc[i][j] += a[i].x * bb[j].x + a[i].y * bb[j].y
                               + a[i].z * bb[j].z + a[i].w * bb[j].w;
        }
#pragma unroll
        for (int i = 0; i < 4; ++i) {
            float4 o;
            o.x = acc[i][0] * 0.125f; o.y = acc[i][1] * 0.125f;
            o.z = acc[i][2] * 0.125f; o.w = acc[i][3] * 0.125f;
            *(float4*)&ss[r0 + i][c0] = o;
        }
    }
    __syncthreads();

    // ---- phase 2: wave-parallel per-row topk/softmax/map/gate/softmax2 ----
    const int ci = lane / 7, cj = lane % 7;     // meaningful for lane < 49
    for (int r = wv; r < NP; r += 4) {
        const float x0 = (lane < NP) ? ss[r][lane] : -INFINITY;

        // bitonic sort ascending across 64 lanes (-INF pads sort low)
        float x = x0;
#pragma unroll
        for (int k = 2; k <= 64; k <<= 1) {
#pragma unroll
            for (int j = k >> 1; j > 0; j >>= 1) {
                const float y = __shfl_xor(x, j);
                const bool takeMin = ((lane & k) == 0) == ((lane & j) == 0);
                x = takeMin ? fminf(x, y) : fmaxf(x, y);
            }
        }
        const float kth = __shfl(x, 53);   // 11th largest = 39th smallest
        const float m1  = __shfl(x, 63);   // row max

        const bool  keep = (lane < NP) && (x0 >= kth);
        const float e   = keep ? expf(x0 - m1) : 0.f;
        const float s   = wsum(e);
        const float smi = wsum(e * (float)ci);
        const float smj = wsum(e * (float)cj);
        const int pi = (int)rintf(smi / s);     // round-half-even == jnp.round
        const int pj = (int)rintf(smj / s);

        const int   R = abs(pi - ci) + abs(pj - cj);
        const float l = (lane < NP) ? fmaxf(x0, 0.f) * vRl[R] : -INFINITY;

        const float m2 = wmax(l);
        const float e2 = (lane < NP) ? expf(l - m2) : 0.f;
        const float s2 = wsum(e2);
        if (lane < NP) ss[r][lane] = e2 / s2;
    }
    __syncthreads();

    // ---- phase 3: mid_slice = p @ v ----
    if (t < 208) {
        const int tr = t >> 4;           // rows 4tr..4tr+3
        const int d0 = (t & 15) << 2;    // output dims d0..d0+3
        float acc[4][4];
#pragma unroll
        for (int i = 0; i < 4; ++i)
#pragma unroll
            for (int j = 0; j < 4; ++j) acc[i][j] = 0.f;
        for (int c = 0; c < NP; ++c) {
            const float4 vv = *(const float4*)&vs[c][d0];
            float p[4];
#pragma unroll
            for (int i = 0; i < 4; ++i) p[i] = ss[4 * tr + i][c];
#pragma unroll
            for (int i = 0; i < 4; ++i) {
                acc[i][0] += p[i] * vv.x;
                acc[i][1] += p[i] * vv.y;
                acc[i][2] += p[i] * vv.z;
                acc[i][3] += p[i] * vv.w;
            }
        }
#pragma unroll
        for (int i = 0; i < 4; ++i) {
            const int r = 4 * tr + i;
            if (r < NP) {
                float4 o;
                o.x = acc[i][0]; o.y = acc[i][1];
                o.z = acc[i][2]; o.w = acc[i][3];
                *(float4*)(mid + base + (size_t)r * NDM + d0) = o;
            }
        }
    }
}

extern "C" void kernel_launch(void* const* d_in, const int* in_sizes, int n_in,
                              void* d_out, int out_size, void* d_ws, size_t ws_size,
                              hipStream_t stream)
{
    (void)in_sizes; (void)n_in; (void)out_size; (void)ws_size;
    const float* queries = (const float*)d_in[0];
    const float* keys    = (const float*)d_in[1];
    const float* values  = (const float*)d_in[2];
    const float* Wq = (const float*)d_in[3];
    const float* bq = (const float*)d_in[4];
    const float* Wk = (const float*)d_in[5];
    const float* bk = (const float*)d_in[6];
    const float* Wv = (const float*)d_in[7];
    const float* bv = (const float*)d_in[8];
    const float* Wo = (const float*)d_in[9];
    const float* bo = (const float*)d_in[10];
    const float* Wg = (const float*)d_in[11];
    const float* Vg = (const float*)d_in[12];
    float* out = (float*)d_out;

    float* ws = (float*)d_ws;
    const size_t SZ = (size_t)NB * NP * NDM;   // 25,690,112 elements
    float* qbuf = ws;
    float* kbuf = ws + SZ;
    float* vbuf = ws + 2 * SZ;
    float* mid  = qbuf;                        // safe alias (see attn_mid)

    const int M = NB * NP;                     // 50176
    dim3 blk(256);
    dim3 ggrid(NDM / BN, M / BM);              // (4, 392)

    hipLaunchKernelGGL(sgemm_nt, ggrid, blk, 0, stream, queries, Wq, bq, qbuf, M, NDM, NDM);
    hipLaunchKernelGGL(sgemm_nt, ggrid, blk, 0, stream, keys,    Wk, bk, kbuf, M, NDM, NDM);
    hipLaunchKernelGGL(mgemm_nt, ggrid, blk, 0, stream, values,  Wv, bv, vbuf, M, NDM, NDM);
    hipLaunchKernelGGL(attn_mid, dim3(NB * NH), blk, 0, stream, qbuf, kbuf, vbuf, Wg, Vg, mid);
    hipLaunchKernelGGL(mgemm_nt, ggrid, blk, 0, stream, mid, Wo, bo, out, M, NDM, NDM);
}